// Round 14
// baseline (412.238 us; speedup 1.0000x reference)
//
#include <hip/hip_runtime.h>

#define HH 1024
#define WW 1024
#define BM 64            // output rows per block
#define BN 256           // output cols per block
#define WAVES 8
#define RPT 8            // output rows per thread (BM / WAVES)
#define TROWS (BM + 10)  // 74 staged input rows
#define TCOLS 264        // staged floats per row: global cols [J0-4 .. J0+259]
#define TFLOATS (TROWS * TCOLS)        // 19536
#define NSTG ((TFLOATS + 255) / 256)   // 77 staging instructions (1 KB each)
#define LDSF (NSTG * 256)              // 19712 floats = 78848 B -> 2 blocks/CU
#define NXCD 8
#define GX (WW / BN)     // 4
#define GY (HH / BM)     // 16

typedef __attribute__((address_space(1))) const float gfloat;
typedef __attribute__((address_space(3))) float sfloat;
typedef float vfloat4 __attribute__((ext_vector_type(4)));   // native vec for nontemporal

__global__ __launch_bounds__(512, 4) void diamond_kernel(const float* __restrict__ in,
                                                         float* __restrict__ out,
                                                         int nblocks) {
    __shared__ __attribute__((aligned(16))) float tile[LDSF];

    // XCD-aware swizzle, gx innermost (proven best, R8).
    const int wgid = blockIdx.x;
    const int k0   = (wgid % NXCD) * (nblocks / NXCD) + wgid / NXCD;
    const int b    = k0 / (GX * GY);
    const int rem  = k0 % (GX * GY);
    const int gy   = rem / GX;
    const int gx   = rem % GX;

    const int tj  = threadIdx.x;                 // lane 0..63
    const int ty  = threadIdx.y;                 // wave 0..7
    const int J0  = gx * BN;
    const int i0b = gy * BM;
    const float* __restrict__ src = in  + (size_t)b * HH * WW;
    float*       __restrict__ dst = out + (size_t)b * HH * WW;

    // ---- stage rows i0b-5 .. i0b+68, global cols [J0-4 .. J0+259] into LDS.
    // tile row r = global row (i0b + r - 5); tile col c = global col (J0-4+c).
#pragma unroll
    for (int n = 0; n < 10; ++n) {
        const int I = ty + 8 * n;                // wave-uniform, 0..79
        if (I < NSTG) {
            const int f = I * 256 + 4 * tj;      // flat float index in tile
            const int r = f / TCOLS;
            const int c = f - r * TCOLS;
            const int gr = (i0b + r - 5) & (HH - 1);
            const int gc = (J0 - 4 + c) & (WW - 1);   // c%4==0 -> 16B aligned
            __builtin_amdgcn_global_load_lds((gfloat*)(src + (size_t)gr * WW + gc),
                                             (sfloat*)&tile[I * 256], 16, 0, 0);
        }
    }
    __syncthreads();   // drains vmcnt(0): all DMAs landed, visible to all waves

    const float EV[6] = {1.0f,
                         0.36787944117144233f,   // e^-1
                         0.1353352832366127f,    // e^-2
                         0.049787068367863944f,  // e^-3
                         0.018315638888734179f,  // e^-4
                         0.006737946999085467f}; // e^-5

    float acc[RPT][4];
#pragma unroll
    for (int m = 0; m < RPT; ++m)
#pragma unroll
        for (int p = 0; p < 4; ++p) acc[m][p] = 0.0f;

    const int base_r = ty * RPT;   // wave's first output row within block

#pragma unroll
    for (int rr = 0; rr < RPT + 10; ++rr) {
        const int tr = base_r + rr;              // tile row 0..73
        const int gr = (i0b + tr - 5) & (HH - 1);
        const float* row = src + (size_t)gr * WW;

        // window s[0..19] = global cols (J0+4tj-8) .. (J0+4tj+11):
        //  far chunks (-8, +8) + center from GLOBAL (coalesced; the same lines
        //  were just DMA'd so they hit L1/L2), near chunks (-4, +4) from LDS.
        const float4 cA = *reinterpret_cast<const float4*>(row + ((J0 + 4 * tj - 8) & (WW - 1)));
        const float4 own = *reinterpret_cast<const float4*>(row + J0 + 4 * tj);
        const float4 cE = *reinterpret_cast<const float4*>(row + ((J0 + 4 * tj + 8) & (WW - 1)));
        const float* trow = &tile[tr * TCOLS + 4 * tj];
        const float4 cB = *reinterpret_cast<const float4*>(trow);       // cols 4tj-4..-1
        const float4 cD = *reinterpret_cast<const float4*>(trow + 8);   // cols 4tj+4..+7

        float s[20];
        s[0]  = cA.x; s[1]  = cA.y; s[2]  = cA.z; s[3]  = cA.w;
        s[4]  = cB.x; s[5]  = cB.y; s[6]  = cB.z; s[7]  = cB.w;
        s[8]  = own.x; s[9] = own.y; s[10] = own.z; s[11] = own.w;
        s[12] = cD.x; s[13] = cD.y; s[14] = cD.z; s[15] = cD.w;
        s[16] = cE.x; s[17] = cE.y; s[18] = cE.z; s[19] = cE.w;

        // level-k horizontal sums consumed on the fly:
        // level k feeds output rows m = rr-k and m = rr-10+k with weight EV[5-k]
        float Hc[4];
#pragma unroll
        for (int p = 0; p < 4; ++p) Hc[p] = s[8 + p];
        {   // k = 0, a = 5
            const int m1 = rr - 10, m2 = rr;
            if (m1 >= 0 && m1 < RPT)
#pragma unroll
                for (int p = 0; p < 4; ++p) acc[m1][p] = fmaf(EV[5], Hc[p], acc[m1][p]);
            if (m2 >= 0 && m2 < RPT)
#pragma unroll
                for (int p = 0; p < 4; ++p) acc[m2][p] = fmaf(EV[5], Hc[p], acc[m2][p]);
        }
#pragma unroll
        for (int k = 1; k <= 4; ++k) {
#pragma unroll
            for (int p = 0; p < 4; ++p)
                Hc[p] = fmaf(EV[k], s[8 + p - k] + s[8 + p + k], Hc[p]);
            const int a = 5 - k;
            const int m1 = rr - 10 + k, m2 = rr - k;
            if (m1 >= 0 && m1 < RPT)
#pragma unroll
                for (int p = 0; p < 4; ++p) acc[m1][p] = fmaf(EV[a], Hc[p], acc[m1][p]);
            if (m2 >= 0 && m2 < RPT && m2 != m1)
#pragma unroll
                for (int p = 0; p < 4; ++p) acc[m2][p] = fmaf(EV[a], Hc[p], acc[m2][p]);
        }
        {   // k = 5 -> center row (a = 0): weight 1, subtract the self term
#pragma unroll
            for (int p = 0; p < 4; ++p)
                Hc[p] = fmaf(EV[5], s[8 + p - 5] + s[8 + p + 5], Hc[p]);
            const int m = rr - 5;
            if (m >= 0 && m < RPT)
#pragma unroll
                for (int p = 0; p < 4; ++p) acc[m][p] += Hc[p] - s[8 + p];
        }
    }

    // non-temporal stores: output is never re-read
#pragma unroll
    for (int m = 0; m < RPT; ++m) {
        vfloat4 v = {acc[m][0], acc[m][1], acc[m][2], acc[m][3]};
        __builtin_nontemporal_store(
            v, reinterpret_cast<vfloat4*>(dst + (size_t)(i0b + base_r + m) * WW + J0 + 4 * tj));
    }
}

extern "C" void kernel_launch(void* const* d_in, const int* in_sizes, int n_in,
                              void* d_out, int out_size, void* d_ws, size_t ws_size,
                              hipStream_t stream) {
    const float* in  = (const float*)d_in[0];
    float*       out = (float*)d_out;
    const int B = in_sizes[0] / (HH * WW);   // 64
    const int nblocks = GX * GY * B;         // 4096, divisible by 8
    dim3 block(64, WAVES, 1);
    dim3 grid(nblocks, 1, 1);
    hipLaunchKernelGGL(diamond_kernel, grid, block, 0, stream, in, out, nblocks);
}

// Round 15
// 115.621 us; speedup vs baseline: 3.5654x; 3.5654x over previous
//
#include <hip/hip_runtime.h>

#define HH 1024
#define WW 1024
#define BM 64            // output rows per block
#define BN 256           // output cols per block
#define WAVES 8
#define RPT 8            // output rows per thread (BM / WAVES)
#define TROWS (BM + 10)  // 74 staged input rows
#define TCOLS 264        // staged floats per row: global cols [J0-4 .. J0+259]
#define TFLOATS (TROWS * TCOLS)        // 19536
#define NSTG ((TFLOATS + 255) / 256)   // 77 staging instructions (1 KB each)
#define LDSF (NSTG * 256)              // 19712 floats = 78848 B -> 2 blocks/CU
#define NXCD 8
#define GX (WW / BN)     // 4
#define GY (HH / BM)     // 16

typedef __attribute__((address_space(1))) const float gfloat;
typedef __attribute__((address_space(3))) float sfloat;
typedef float vfloat4 __attribute__((ext_vector_type(4)));   // native vec for nontemporal

__global__ __launch_bounds__(512) void diamond_kernel(const float* __restrict__ in,
                                                      float* __restrict__ out,
                                                      int nblocks) {
    __shared__ __attribute__((aligned(16))) float tile[LDSF];

    // XCD-aware swizzle, gx innermost (proven best, R8).
    const int wgid = blockIdx.x;
    const int k0   = (wgid % NXCD) * (nblocks / NXCD) + wgid / NXCD;
    const int b    = k0 / (GX * GY);
    const int rem  = k0 % (GX * GY);
    const int gy   = rem / GX;
    const int gx   = rem % GX;

    const int tj  = threadIdx.x;                 // lane 0..63
    const int ty  = threadIdx.y;                 // wave 0..7
    const int J0  = gx * BN;
    const int i0b = gy * BM;
    const float* __restrict__ src = in  + (size_t)b * HH * WW;
    float*       __restrict__ dst = out + (size_t)b * HH * WW;

    // ---- stage rows i0b-5 .. i0b+68, global cols [J0-4 .. J0+259] into LDS.
    // tile row r = global row (i0b + r - 5); tile col c = global col (J0-4+c).
#pragma unroll
    for (int n = 0; n < 10; ++n) {
        const int I = ty + 8 * n;                // wave-uniform, 0..79
        if (I < NSTG) {
            const int f = I * 256 + 4 * tj;      // flat float index in tile
            const int r = f / TCOLS;
            const int c = f - r * TCOLS;
            const int gr = (i0b + r - 5) & (HH - 1);
            const int gc = (J0 - 4 + c) & (WW - 1);   // c%4==0 -> 16B aligned
            __builtin_amdgcn_global_load_lds((gfloat*)(src + (size_t)gr * WW + gc),
                                             (sfloat*)&tile[I * 256], 16, 0, 0);
        }
    }
    __syncthreads();   // drains vmcnt(0): all DMAs landed, visible to all waves

    const float EV[6] = {1.0f,
                         0.36787944117144233f,   // e^-1
                         0.1353352832366127f,    // e^-2
                         0.049787068367863944f,  // e^-3
                         0.018315638888734179f,  // e^-4
                         0.006737946999085467f}; // e^-5

    float acc[RPT][4];
#pragma unroll
    for (int m = 0; m < RPT; ++m)
#pragma unroll
        for (int p = 0; p < 4; ++p) acc[m][p] = 0.0f;

    const int base_r = ty * RPT;   // wave's first output row within block

#pragma unroll
    for (int rr = 0; rr < RPT + 10; ++rr) {
        const int tr = base_r + rr;              // tile row 0..73
        const int gr = (i0b + tr - 5) & (HH - 1);
        const float* row = src + (size_t)gr * WW;

        // window s[0..19] = global cols (J0+4tj-8) .. (J0+4tj+11):
        //  far chunks (-8, +8) + center from GLOBAL (coalesced; the same lines
        //  were just DMA'd so they hit L1/L2), near chunks (-4, +4) from LDS.
        const float4 cA = *reinterpret_cast<const float4*>(row + ((J0 + 4 * tj - 8) & (WW - 1)));
        const float4 own = *reinterpret_cast<const float4*>(row + J0 + 4 * tj);
        const float4 cE = *reinterpret_cast<const float4*>(row + ((J0 + 4 * tj + 8) & (WW - 1)));
        const float* trow = &tile[tr * TCOLS + 4 * tj];
        const float4 cB = *reinterpret_cast<const float4*>(trow);       // cols 4tj-4..-1
        const float4 cD = *reinterpret_cast<const float4*>(trow + 8);   // cols 4tj+4..+7

        float s[20];
        s[0]  = cA.x; s[1]  = cA.y; s[2]  = cA.z; s[3]  = cA.w;
        s[4]  = cB.x; s[5]  = cB.y; s[6]  = cB.z; s[7]  = cB.w;
        s[8]  = own.x; s[9] = own.y; s[10] = own.z; s[11] = own.w;
        s[12] = cD.x; s[13] = cD.y; s[14] = cD.z; s[15] = cD.w;
        s[16] = cE.x; s[17] = cE.y; s[18] = cE.z; s[19] = cE.w;

        // level-k horizontal sums consumed on the fly:
        // level k feeds output rows m = rr-k and m = rr-10+k with weight EV[5-k]
        float Hc[4];
#pragma unroll
        for (int p = 0; p < 4; ++p) Hc[p] = s[8 + p];
        {   // k = 0, a = 5
            const int m1 = rr - 10, m2 = rr;
            if (m1 >= 0 && m1 < RPT)
#pragma unroll
                for (int p = 0; p < 4; ++p) acc[m1][p] = fmaf(EV[5], Hc[p], acc[m1][p]);
            if (m2 >= 0 && m2 < RPT)
#pragma unroll
                for (int p = 0; p < 4; ++p) acc[m2][p] = fmaf(EV[5], Hc[p], acc[m2][p]);
        }
#pragma unroll
        for (int k = 1; k <= 4; ++k) {
#pragma unroll
            for (int p = 0; p < 4; ++p)
                Hc[p] = fmaf(EV[k], s[8 + p - k] + s[8 + p + k], Hc[p]);
            const int a = 5 - k;
            const int m1 = rr - 10 + k, m2 = rr - k;
            if (m1 >= 0 && m1 < RPT)
#pragma unroll
                for (int p = 0; p < 4; ++p) acc[m1][p] = fmaf(EV[a], Hc[p], acc[m1][p]);
            if (m2 >= 0 && m2 < RPT && m2 != m1)
#pragma unroll
                for (int p = 0; p < 4; ++p) acc[m2][p] = fmaf(EV[a], Hc[p], acc[m2][p]);
        }
        {   // k = 5 -> center row (a = 0): weight 1, subtract the self term
#pragma unroll
            for (int p = 0; p < 4; ++p)
                Hc[p] = fmaf(EV[5], s[8 + p - 5] + s[8 + p + 5], Hc[p]);
            const int m = rr - 5;
            if (m >= 0 && m < RPT)
#pragma unroll
                for (int p = 0; p < 4; ++p) acc[m][p] += Hc[p] - s[8 + p];
        }
    }

    // non-temporal stores: output is never re-read
#pragma unroll
    for (int m = 0; m < RPT; ++m) {
        vfloat4 v = {acc[m][0], acc[m][1], acc[m][2], acc[m][3]};
        __builtin_nontemporal_store(
            v, reinterpret_cast<vfloat4*>(dst + (size_t)(i0b + base_r + m) * WW + J0 + 4 * tj));
    }
}

extern "C" void kernel_launch(void* const* d_in, const int* in_sizes, int n_in,
                              void* d_out, int out_size, void* d_ws, size_t ws_size,
                              hipStream_t stream) {
    const float* in  = (const float*)d_in[0];
    float*       out = (float*)d_out;
    const int B = in_sizes[0] / (HH * WW);   // 64
    const int nblocks = GX * GY * B;         // 4096, divisible by 8
    dim3 block(64, WAVES, 1);
    dim3 grid(nblocks, 1, 1);
    hipLaunchKernelGGL(diamond_kernel, grid, block, 0, stream, in, out, nblocks);
}